// Round 18
// baseline (41.241 us; speedup 1.0000x reference)
//
#include <hip/hip_runtime.h>
#include <math.h>

// Problem constants: z [4,32,32,32] f32, embedding [32768,32] f32.
constexpr int Bc   = 4;
constexpr int Dc   = 32;
constexpr int HWc  = 1024;
constexpr int NE   = 32768;
constexpr int POS  = Bc * HWc;        // 4096 positions

constexpr int CCODES = 256;           // codes per chunk (32 KB hi+lo in LDS)
constexpr int NCHUNK = NE / CCODES;   // 128
constexpr int PPB    = 512;           // positions per phase-A block (8 waves x 64)
constexpr int NPBLK  = POS / PPB;     // 8

typedef _Float16 f16x8 __attribute__((ext_vector_type(8)));
typedef float    f32x4 __attribute__((ext_vector_type(4)));
typedef unsigned long long u64;

// Monotonic float->uint order-preserving encode; pack with ~k so equal
// values -> smaller k wins under max (jnp.argmax first-index rule).
__device__ inline unsigned encF(float v) {
    unsigned u = __float_as_uint(v);
    return (u & 0x80000000u) ? ~u : (u | 0x80000000u);
}
__device__ inline u64 packVK(float v, int k) {
    return ((u64)encF(v) << 32) | (unsigned)(~k);
}

// Prep: split-fp16. Blocks 0..127: emb -> Es [32768][64] (hi 0..31, lo
// 32..63; hi+lo = x to ~2^-22). Blocks 128..143: z -> Zs [4096][64] and
// zero best2.
__global__ __launch_bounds__(256) void vq_eprep(
    const float* __restrict__ emb, const float* __restrict__ z,
    _Float16* __restrict__ Es, _Float16* __restrict__ Zs,
    u64* __restrict__ best2)
{
    float x[Dc];
    _Float16* dptr;
    if (blockIdx.x < NE / 256) {
        const int c = blockIdx.x * 256 + threadIdx.x;
        const float4* src = reinterpret_cast<const float4*>(emb + (size_t)c * Dc);
#pragma unroll
        for (int q = 0; q < 8; ++q) {
            const float4 v = src[q];
            x[4*q+0] = v.x; x[4*q+1] = v.y; x[4*q+2] = v.z; x[4*q+3] = v.w;
        }
        dptr = Es + (size_t)c * 64;
    } else {
        const int p = (blockIdx.x - NE / 256) * 256 + threadIdx.x;
        best2[p] = 0ULL;   // below any encoded real
        const int b = p >> 10, hw = p & (HWc - 1);
        const float* zp = z + (size_t)b * Dc * HWc + hw;
#pragma unroll
        for (int d = 0; d < Dc; ++d) x[d] = zp[(size_t)d * HWc];
        dptr = Zs + (size_t)p * 64;
    }
    f16x8* dst = reinterpret_cast<f16x8*>(dptr);
#pragma unroll
    for (int q = 0; q < 4; ++q) {
        f16x8 h, l;
#pragma unroll
        for (int r = 0; r < 8; ++r) {
            const float xv = x[8*q+r];
            const _Float16 hv = (_Float16)xv;
            h[r] = hv;
            l[r] = (_Float16)(xv - (float)hv);
        }
        dst[q]     = h;
        dst[4 + q] = l;
    }
}

// Phase A: EXACT split-fp16 MFMA (hi*hi + hi*lo + lo*hi; bit-proven absmax 0
// since r8), value-only tracking (r17-proven). Round-18: 4 pos-tiles/wave
// (64 positions) -- value-only freed the registers that blocked this in r13.
// Halves wave count (8192): LDS-pipe reads 524k->262k, per-wave prologue +
// staging issue + tail commits halve, MFMA total unchanged. ~90 live regs.
__global__ __launch_bounds__(512)
__attribute__((amdgpu_waves_per_eu(4, 8)))
void vq_phaseA(
    const _Float16* __restrict__ Zs, const _Float16* __restrict__ Es,
    u64* __restrict__ best2)
{
    __shared__ __align__(16) char lds[PPB * 17 * 4];   // 34816 B (tail bound)

    const int lin  = blockIdx.x;               // 0..1023
    const int xcd  = lin & 7;
    const int j    = lin >> 3;
    const int chunk = xcd * (NCHUNK / 8) + (j & (NCHUNK / 8 - 1));
    const int pblk  = j >> 4;                  // 0..7
    const int tid  = threadIdx.x;
    const int wave = tid >> 6, lane = tid & 63;
    const int m = lane & 15, g = lane >> 4;

    // stage chunk (hi+lo rows) -> LDS, pre-swizzled source (r10-proven)
    {
        const char* src = (const char*)(Es + (size_t)chunk * CCODES * 64);
        char* dstbase = lds + wave * 1024;
#pragma unroll
        for (int r = 0; r < 4; ++r) {
            const int o    = r * 512 + tid;
            const int row  = o >> 3;
            const int ccol = o & 7;
            const int soff = row * 128 + ((ccol ^ (row & 7)) << 4);
            __builtin_amdgcn_global_load_lds(
                (const __attribute__((address_space(1))) void*)(src + soff),
                (__attribute__((address_space(3))) void*)(dstbase + r * 8192),
                16, 0, 0);
        }
    }

    const int posBase0 = pblk * PPB;
    const int posBase  = posBase0 + wave * 64;
    f16x8 Ahi[4], Alo[4];
#pragma unroll
    for (int t = 0; t < 4; ++t) {
        const _Float16* zrow = Zs + (size_t)(posBase + t * 16 + m) * 64 + 8 * g;
        Ahi[t] = *reinterpret_cast<const f16x8*>(zrow);
        Alo[t] = *reinterpret_cast<const f16x8*>(zrow + 32);
    }
#pragma unroll
    for (int t = 0; t < 4; ++t) asm volatile("" : "+v"(Ahi[t]), "+v"(Alo[t]));

    f32x4 zacc = {0.f, 0.f, 0.f, 0.f};
    asm volatile("" : "+v"(zacc));

    float bval[16];
#pragma unroll
    for (int i = 0; i < 16; ++i) bval[i] = -INFINITY;

    __syncthreads();

    const char* lbase = lds;
    const int off_h = m * 128 + (( g      ^ (m & 7)) << 4);
    const int off_l = m * 128 + (((g + 4) ^ (m & 7)) << 4);

#pragma unroll 2
    for (int ct = 0; ct < CCODES / 16; ct += 2) {      // tile pairs
        const char* p0 = lbase + ct * 2048;
        const f16x8 Bh0 = *reinterpret_cast<const f16x8*>(p0 + off_h);
        const f16x8 Bl0 = *reinterpret_cast<const f16x8*>(p0 + off_l);
        const f16x8 Bh1 = *reinterpret_cast<const f16x8*>(p0 + 2048 + off_h);
        const f16x8 Bl1 = *reinterpret_cast<const f16x8*>(p0 + 2048 + off_l);

#pragma unroll
        for (int t = 0; t < 4; ++t) {
            f32x4 aA, aB;      // two independent exact 3-product chains
            aA = __builtin_amdgcn_mfma_f32_16x16x32_f16(Ahi[t], Bh0, zacc, 0, 0, 0);
            aB = __builtin_amdgcn_mfma_f32_16x16x32_f16(Ahi[t], Bh1, zacc, 0, 0, 0);
            aA = __builtin_amdgcn_mfma_f32_16x16x32_f16(Ahi[t], Bl0, aA,  0, 0, 0);
            aB = __builtin_amdgcn_mfma_f32_16x16x32_f16(Ahi[t], Bl1, aB,  0, 0, 0);
            aA = __builtin_amdgcn_mfma_f32_16x16x32_f16(Alo[t], Bh0, aA,  0, 0, 0);
            aB = __builtin_amdgcn_mfma_f32_16x16x32_f16(Alo[t], Bh1, aB,  0, 0, 0);
#pragma unroll
            for (int r = 0; r < 4; ++r)
                bval[t*4+r] = fmaxf(fmaxf(bval[t*4+r], aA[r]), aB[r]);  // max3
        }
    }

    // tail: value-only LDS reduce, then (val, ~chunk) u64 atomic per position
    __syncthreads();
    float* red = reinterpret_cast<float*>(lds);        // [512][17] f32
#pragma unroll
    for (int i = 0; i < 16; ++i) {
        const int t = i >> 2, r = i & 3;
        const int row = wave * 64 + t * 16 + 4 * g + r;
        red[row * 17 + m] = bval[i];
    }
    __syncthreads();
    {
        float mx = red[tid * 17];
#pragma unroll
        for (int mm = 1; mm < 16; ++mm) mx = fmaxf(mx, red[tid * 17 + mm]);
        atomicMax(best2 + posBase0 + tid, packVK(mx, chunk));
    }
}

// Phase B: one wave per position (r17-proven). Decode winning chunk, rescan
// its 256 codes with scalar fp32 dots (8-lane group per code, coalesced
// float4 loads), shuffle-reduce, packed-u64 butterfly, then lanes 0..31
// gather e[idx] and write z_q + ind directly.
__global__ __launch_bounds__(256) void vq_phaseB(
    const float* __restrict__ z, const float* __restrict__ emb,
    const u64* __restrict__ best2, float* __restrict__ zq,
    float* __restrict__ indOut)
{
    const int p    = blockIdx.x * 4 + (threadIdx.x >> 6);   // 0..4095
    const int lane = threadIdx.x & 63;

    const int chunk = (int)(~(unsigned)best2[p]) & (NCHUNK - 1);
    const int cbase = chunk * CCODES;
    const int b = p >> 10, hw = p & (HWc - 1);

    const int d0 = (lane & 7) * 4;
    const float* zp = z + (size_t)b * Dc * HWc + hw;
    const float z0 = zp[(size_t)(d0 + 0) * HWc];
    const float z1 = zp[(size_t)(d0 + 1) * HWc];
    const float z2 = zp[(size_t)(d0 + 2) * HWc];
    const float z3 = zp[(size_t)(d0 + 3) * HWc];

    const float4* eb = reinterpret_cast<const float4*>(emb + (size_t)cbase * Dc);

    float bv = -INFINITY;
    int   bi = cbase;
#pragma unroll 4
    for (int s = 0; s < 32; ++s) {                 // 8 codes per sweep
        const float4 ev = eb[s * 64 + lane];
        float d = z0 * ev.x + z1 * ev.y;
        d = fmaf(z2, ev.z, d);
        d = fmaf(z3, ev.w, d);
        d += __shfl_xor(d, 1, 64);                 // reduce 8-lane group
        d += __shfl_xor(d, 2, 64);
        d += __shfl_xor(d, 4, 64);
        const int code = cbase + s * 8 + (lane >> 3);
        const bool up = d > bv;                    // ascending s: first idx
        bi = up ? code : bi;
        bv = fmaxf(bv, d);
    }

    u64 pk = packVK(bv, bi);
#pragma unroll
    for (int s = 8; s < 64; s <<= 1) {
        const u64 o = __shfl_xor(pk, s, 64);
        if (o > pk) pk = o;
    }
    const int widx = (int)(~(unsigned)pk);

    if (lane < Dc) {
        const float ev = emb[(size_t)widx * Dc + lane];
        zq[(size_t)b * Dc * HWc + (size_t)lane * HWc + hw] = ev;
    }
    if (lane == 0) indOut[p] = (float)widx;        // <=32767: exact in fp32
}

// Fallback (ws too small): scalar VALU scan + finish.
__global__ __launch_bounds__(256, 4) void vq_scalar(
    const float* __restrict__ z, const float* __restrict__ emb,
    u64* __restrict__ best)
{
    const int lin = blockIdx.x;
    const int xcd = lin & 7, j = lin >> 3;
    const int seg    = xcd * 32 + (j & 31);
    const int posgrp = j >> 5;

    const int t  = posgrp * 256 + threadIdx.x;
    const int p0 = t, p1 = t + POS / 2;
    const int b0 = p0 >> 10, hw0 = p0 & (HWc - 1);
    const int b1 = p1 >> 10, hw1 = p1 & (HWc - 1);
    const float* zp0 = z + (size_t)b0 * Dc * HWc + hw0;
    const float* zp1 = z + (size_t)b1 * Dc * HWc + hw1;

    float za[Dc], zb[Dc];
#pragma unroll
    for (int d = 0; d < Dc; ++d) {
        za[d] = zp0[(size_t)d * HWc];
        zb[d] = zp1[(size_t)d * HWc];
    }
#pragma unroll
    for (int d = 0; d < Dc; ++d) asm volatile("" : "+v"(za[d]), "+v"(zb[d]));

    const int c0 = seg * 128;
    const float4* e4 = reinterpret_cast<const float4*>(emb + (size_t)c0 * Dc);
    float v0 = -INFINITY, v1 = -INFINITY;
    int   i0 = c0, i1 = c0;
#pragma unroll 1
    for (int cc = 0; cc < 128; ++cc, e4 += 8) {
        float a0 = 0.f, a1 = 0.f;
#pragma unroll
        for (int q = 0; q < 8; ++q) {
            const float4 e = e4[q];
            a0 = fmaf(za[4*q+0], e.x, a0); a1 = fmaf(zb[4*q+0], e.x, a1);
            a0 = fmaf(za[4*q+1], e.y, a0); a1 = fmaf(zb[4*q+1], e.y, a1);
            a0 = fmaf(za[4*q+2], e.z, a0); a1 = fmaf(zb[4*q+2], e.z, a1);
            a0 = fmaf(za[4*q+3], e.w, a0); a1 = fmaf(zb[4*q+3], e.w, a1);
        }
        const int c = c0 + cc;
        if (a0 > v0) { v0 = a0; i0 = c; }
        if (a1 > v1) { v1 = a1; i1 = c; }
    }
    atomicMax(best + p0, packVK(v0, i0));
    atomicMax(best + p1, packVK(v1, i1));
}

__global__ __launch_bounds__(256) void vq_finish_kernel(
    const u64* __restrict__ best, const float* __restrict__ emb,
    float* __restrict__ zq, float* __restrict__ indOut)
{
    const int p = blockIdx.x * 256 + threadIdx.x;
    const int idx = (int)(~(unsigned)best[p]);

    const float4* e = reinterpret_cast<const float4*>(emb + (size_t)idx * Dc);
    const int b  = p >> 10;
    const int hw = p & (HWc - 1);
    float* o = zq + (size_t)b * Dc * HWc + hw;
#pragma unroll
    for (int q = 0; q < 8; ++q) {
        const float4 v = e[q];
        o[(size_t)(4*q+0) * HWc] = v.x;
        o[(size_t)(4*q+1) * HWc] = v.y;
        o[(size_t)(4*q+2) * HWc] = v.z;
        o[(size_t)(4*q+3) * HWc] = v.w;
    }
    indOut[p] = (float)idx;
}

extern "C" void kernel_launch(void* const* d_in, const int* in_sizes, int n_in,
                              void* d_out, int out_size, void* d_ws, size_t ws_size,
                              hipStream_t stream)
{
    const float* z   = (const float*)d_in[0];
    const float* emb = (const float*)d_in[1];

    float* out    = (float*)d_out;
    float* zq     = out;
    float* indOut = out + (size_t)Bc * Dc * HWc;

    char* w = (char*)d_ws;
    u64*      best2 = (u64*)w;          w += (size_t)POS * 8;
    _Float16* Es    = (_Float16*)w;     w += (size_t)NE * 64 * 2;
    _Float16* Zs    = (_Float16*)w;
    const size_t needed = (size_t)POS * 8 + (size_t)(NE + POS) * 64 * 2;

    if (ws_size >= needed) {
        hipLaunchKernelGGL(vq_eprep, dim3(NE / 256 + POS / 256), dim3(256), 0,
                           stream, emb, z, Es, Zs, best2);
        hipLaunchKernelGGL(vq_phaseA, dim3(NCHUNK * NPBLK), dim3(512), 0,
                           stream, Zs, Es, best2);
        hipLaunchKernelGGL(vq_phaseB, dim3(POS / 4), dim3(256), 0, stream,
                           z, emb, best2, zq, indOut);
    } else {
        hipMemsetAsync(best2, 0, (size_t)POS * sizeof(u64), stream);
        hipLaunchKernelGGL(vq_scalar, dim3(2048), dim3(256), 0, stream,
                           z, emb, best2);
        hipLaunchKernelGGL(vq_finish_kernel, dim3(POS / 256), dim3(256), 0,
                           stream, best2, emb, zq, indOut);
    }
}

// Round 19
// 37.319 us; speedup vs baseline: 1.1051x; 1.1051x over previous
//
#include <hip/hip_runtime.h>
#include <math.h>

// Problem constants: z [4,32,32,32] f32, embedding [32768,32] f32.
constexpr int Bc   = 4;
constexpr int Dc   = 32;
constexpr int HWc  = 1024;
constexpr int NE   = 32768;
constexpr int POS  = Bc * HWc;        // 4096 positions

constexpr int CCODES = 256;           // codes per chunk (32 KB in LDS)
constexpr int NCHUNK = NE / CCODES;   // 128
constexpr int PPB    = 512;           // positions per phase-A block (8 waves x 64)
constexpr int NPBLK  = POS / PPB;     // 8

typedef _Float16 f16x8 __attribute__((ext_vector_type(8)));
typedef float    f32x4 __attribute__((ext_vector_type(4)));
typedef unsigned long long u64;

// Monotonic float->uint order-preserving encode; pack with ~k so equal
// values -> smaller k wins under max (jnp.argmax first-index rule).
__device__ inline unsigned encF(float v) {
    unsigned u = __float_as_uint(v);
    return (u & 0x80000000u) ? ~u : (u | 0x80000000u);
}
__device__ inline u64 packVK(float v, int k) {
    return ((u64)encF(v) << 32) | (unsigned)(~k);
}

// Phase A (fused, no eprep): stage RAW fp32 chunk -> LDS, convert in-LDS to
// split-fp16 (r12-proven own-row mechanics), A-frags split in-reg from raw z
// (r10-proven), then the bit-proven exact 3-product MFMA scan with value-only
// tracking (r17/r18). Tail: PLAIN coalesced-ish store of encoded per-
// (pos,chunk) max into pcmax[pos][128] -- no atomics, no init required
// (fully overwritten every run -> deterministic + poison-proof).
__global__ __launch_bounds__(512)
__attribute__((amdgpu_waves_per_eu(4, 8)))
void vq_phaseA(
    const float* __restrict__ z, const float* __restrict__ emb,
    unsigned* __restrict__ pcmax)
{
    __shared__ __align__(16) char lds[PPB * 17 * 4];   // 34816 B (tail bound)

    const int lin  = blockIdx.x;               // 0..1023
    const int xcd  = lin & 7;                  // dispatch round-robins XCDs
    const int j    = lin >> 3;                 // 0..127
    const int chunk = xcd * (NCHUNK / 8) + (j & (NCHUNK / 8 - 1));
    const int pblk  = j >> 4;                  // 0..7
    const int tid  = threadIdx.x;
    const int wave = tid >> 6, lane = tid & 63;
    const int m = lane & 15, g = lane >> 4;

    // ---- stage RAW fp32 chunk -> LDS, pre-swizzled source (r12 pattern) ----
    {
        const char* src = (const char*)(emb + (size_t)chunk * CCODES * Dc);
        char* dstbase = lds + wave * 1024;
#pragma unroll
        for (int r = 0; r < 4; ++r) {
            const int o    = r * 512 + tid;          // 16B-chunk index 0..2047
            const int row  = o >> 3;                 // code row 0..255
            const int ccol = o & 7;                  // 16B col 0..7
            const int soff = row * 128 + ((ccol ^ (row & 7)) << 4);
            __builtin_amdgcn_global_load_lds(
                (const __attribute__((address_space(1))) void*)(src + soff),
                (__attribute__((address_space(3))) void*)(dstbase + r * 8192),
                16, 0, 0);
        }
    }

    // ---- A fragments: in-reg split-fp16 from raw z (overlaps staging) ----
    const int posBase0 = pblk * PPB;
    const int posBase  = posBase0 + wave * 64;
    f16x8 Ahi[4], Alo[4];
#pragma unroll
    for (int t = 0; t < 4; ++t) {
        const int pos = posBase + t * 16 + m;
        const int b = pos >> 10, hw = pos & (HWc - 1);
        const float* zp = z + (size_t)b * Dc * HWc + hw;
#pragma unroll
        for (int q = 0; q < 8; ++q) {
            const float xv = zp[(size_t)(8 * g + q) * HWc];
            const _Float16 hv = (_Float16)xv;
            Ahi[t][q] = hv;
            Alo[t][q] = (_Float16)(xv - (float)hv);
        }
    }
#pragma unroll
    for (int t = 0; t < 4; ++t) asm volatile("" : "+v"(Ahi[t]), "+v"(Alo[t]));

    f32x4 zacc = {0.f, 0.f, 0.f, 0.f};
    asm volatile("" : "+v"(zacc));     // persistent zero C-operand quad

    float bval[16];
#pragma unroll
    for (int i = 0; i < 16; ++i) bval[i] = -INFINITY;

    __syncthreads();   // staging complete

    // ---- in-LDS convert fp32 -> split-fp16, thread t<256 owns row t ----
    // (read own row, write own row: race-free; r12-proven)
    if (tid < 256) {
        char* myrow = lds + tid * 128;
        float4 raw[8];
#pragma unroll
        for (int c = 0; c < 8; ++c)
            raw[c] = *reinterpret_cast<const float4*>(myrow + ((c ^ (tid & 7)) << 4));
        f16x8 h[4], l[4];
#pragma unroll
        for (int cc = 0; cc < 4; ++cc) {
            const float4 a = raw[2 * cc], bq = raw[2 * cc + 1];
            const float xs[8] = {a.x, a.y, a.z, a.w, bq.x, bq.y, bq.z, bq.w};
#pragma unroll
            for (int r = 0; r < 8; ++r) {
                const _Float16 hv = (_Float16)xs[r];
                h[cc][r] = hv;
                l[cc][r] = (_Float16)(xs[r] - (float)hv);
            }
        }
#pragma unroll
        for (int cc = 0; cc < 4; ++cc) {
            *reinterpret_cast<f16x8*>(myrow + (( cc      ^ (tid & 7)) << 4)) = h[cc];
            *reinterpret_cast<f16x8*>(myrow + (((cc + 4) ^ (tid & 7)) << 4)) = l[cc];
        }
    }
    __syncthreads();   // convert complete

    // ---- hot loop: exact 3-product, value-only (bit-proven since r8) ----
    const char* lbase = lds;
    const int off_h = m * 128 + (( g      ^ (m & 7)) << 4);
    const int off_l = m * 128 + (((g + 4) ^ (m & 7)) << 4);

#pragma unroll 2
    for (int ct = 0; ct < CCODES / 16; ct += 2) {      // tile pairs
        const char* p0 = lbase + ct * 2048;
        const f16x8 Bh0 = *reinterpret_cast<const f16x8*>(p0 + off_h);
        const f16x8 Bl0 = *reinterpret_cast<const f16x8*>(p0 + off_l);
        const f16x8 Bh1 = *reinterpret_cast<const f16x8*>(p0 + 2048 + off_h);
        const f16x8 Bl1 = *reinterpret_cast<const f16x8*>(p0 + 2048 + off_l);

#pragma unroll
        for (int t = 0; t < 4; ++t) {
            f32x4 aA, aB;      // two independent exact 3-product chains
            aA = __builtin_amdgcn_mfma_f32_16x16x32_f16(Ahi[t], Bh0, zacc, 0, 0, 0);
            aB = __builtin_amdgcn_mfma_f32_16x16x32_f16(Ahi[t], Bh1, zacc, 0, 0, 0);
            aA = __builtin_amdgcn_mfma_f32_16x16x32_f16(Ahi[t], Bl0, aA,  0, 0, 0);
            aB = __builtin_amdgcn_mfma_f32_16x16x32_f16(Ahi[t], Bl1, aB,  0, 0, 0);
            aA = __builtin_amdgcn_mfma_f32_16x16x32_f16(Alo[t], Bh0, aA,  0, 0, 0);
            aB = __builtin_amdgcn_mfma_f32_16x16x32_f16(Alo[t], Bh1, aB,  0, 0, 0);
#pragma unroll
            for (int r = 0; r < 4; ++r)
                bval[t*4+r] = fmaxf(fmaxf(bval[t*4+r], aA[r]), aB[r]);  // max3
        }
    }

    // ---- tail: value-only LDS reduce, plain store (no atomics) ----
    __syncthreads();                    // all waves done reading B
    float* red = reinterpret_cast<float*>(lds);        // [512][17] f32
#pragma unroll
    for (int i = 0; i < 16; ++i) {
        const int t = i >> 2, r = i & 3;
        const int row = wave * 64 + t * 16 + 4 * g + r;
        red[row * 17 + m] = bval[i];
    }
    __syncthreads();
    {
        float mx = red[tid * 17];
#pragma unroll
        for (int mm = 1; mm < 16; ++mm) mx = fmaxf(mx, red[tid * 17 + mm]);
        pcmax[(size_t)(posBase0 + tid) * NCHUNK + chunk] = encF(mx);
    }
}

// Phase B: one wave per position. Reduce the 128 chunk candidates (2
// coalesced u32 loads + packed-u64 butterfly, first-chunk tie-break), then
// rescan the winning chunk with exact fp32 scalar dots (r17-proven) and
// write z_q + ind directly.
__global__ __launch_bounds__(256) void vq_phaseB(
    const float* __restrict__ z, const float* __restrict__ emb,
    const unsigned* __restrict__ pcmax, float* __restrict__ zq,
    float* __restrict__ indOut)
{
    const int p    = blockIdx.x * 4 + (threadIdx.x >> 6);   // 0..4095
    const int lane = threadIdx.x & 63;

    // ---- chunk selection: max over 128 encoded maxima ----
    const unsigned v0 = pcmax[(size_t)p * NCHUNK + lane];
    const unsigned v1 = pcmax[(size_t)p * NCHUNK + 64 + lane];
    u64 pk0 = ((u64)v0 << 32) | (unsigned)(~lane);
    u64 pk1 = ((u64)v1 << 32) | (unsigned)(~(64 + lane));
    u64 pk = pk0 > pk1 ? pk0 : pk1;     // equal val -> smaller chunk wins
#pragma unroll
    for (int s = 1; s < 64; s <<= 1) {
        const u64 o = __shfl_xor(pk, s, 64);
        if (o > pk) pk = o;
    }
    const int chunk = (int)(~(unsigned)pk) & (NCHUNK - 1);
    const int cbase = chunk * CCODES;
    const int b = p >> 10, hw = p & (HWc - 1);

    // ---- exact fp32 rescan of the winning chunk ----
    const int d0 = (lane & 7) * 4;
    const float* zp = z + (size_t)b * Dc * HWc + hw;
    const float z0 = zp[(size_t)(d0 + 0) * HWc];
    const float z1 = zp[(size_t)(d0 + 1) * HWc];
    const float z2 = zp[(size_t)(d0 + 2) * HWc];
    const float z3 = zp[(size_t)(d0 + 3) * HWc];

    const float4* eb = reinterpret_cast<const float4*>(emb + (size_t)cbase * Dc);

    float bv = -INFINITY;
    int   bi = cbase;
#pragma unroll 4
    for (int s = 0; s < 32; ++s) {                 // 8 codes per sweep
        const float4 ev = eb[s * 64 + lane];
        float d = z0 * ev.x + z1 * ev.y;
        d = fmaf(z2, ev.z, d);
        d = fmaf(z3, ev.w, d);
        d += __shfl_xor(d, 1, 64);                 // reduce 8-lane group
        d += __shfl_xor(d, 2, 64);
        d += __shfl_xor(d, 4, 64);
        const int code = cbase + s * 8 + (lane >> 3);
        const bool up = d > bv;                    // ascending s: first idx
        bi = up ? code : bi;
        bv = fmaxf(bv, d);
    }

    u64 pki = packVK(bv, bi);
#pragma unroll
    for (int s = 8; s < 64; s <<= 1) {
        const u64 o = __shfl_xor(pki, s, 64);
        if (o > pki) pki = o;
    }
    const int widx = (int)(~(unsigned)pki);

    if (lane < Dc) {
        const float ev = emb[(size_t)widx * Dc + lane];
        zq[(size_t)b * Dc * HWc + (size_t)lane * HWc + hw] = ev;
    }
    if (lane == 0) indOut[p] = (float)widx;        // <=32767: exact in fp32
}

// Fallback (ws too small for pcmax): scalar VALU scan + finish.
__global__ __launch_bounds__(256, 4) void vq_scalar(
    const float* __restrict__ z, const float* __restrict__ emb,
    u64* __restrict__ best)
{
    const int lin = blockIdx.x;
    const int xcd = lin & 7, j = lin >> 3;
    const int seg    = xcd * 32 + (j & 31);
    const int posgrp = j >> 5;

    const int t  = posgrp * 256 + threadIdx.x;
    const int p0 = t, p1 = t + POS / 2;
    const int b0 = p0 >> 10, hw0 = p0 & (HWc - 1);
    const int b1 = p1 >> 10, hw1 = p1 & (HWc - 1);
    const float* zp0 = z + (size_t)b0 * Dc * HWc + hw0;
    const float* zp1 = z + (size_t)b1 * Dc * HWc + hw1;

    float za[Dc], zb[Dc];
#pragma unroll
    for (int d = 0; d < Dc; ++d) {
        za[d] = zp0[(size_t)d * HWc];
        zb[d] = zp1[(size_t)d * HWc];
    }
#pragma unroll
    for (int d = 0; d < Dc; ++d) asm volatile("" : "+v"(za[d]), "+v"(zb[d]));

    const int c0 = seg * 128;
    const float4* e4 = reinterpret_cast<const float4*>(emb + (size_t)c0 * Dc);
    float v0 = -INFINITY, v1 = -INFINITY;
    int   i0 = c0, i1 = c0;
#pragma unroll 1
    for (int cc = 0; cc < 128; ++cc, e4 += 8) {
        float a0 = 0.f, a1 = 0.f;
#pragma unroll
        for (int q = 0; q < 8; ++q) {
            const float4 e = e4[q];
            a0 = fmaf(za[4*q+0], e.x, a0); a1 = fmaf(zb[4*q+0], e.x, a1);
            a0 = fmaf(za[4*q+1], e.y, a0); a1 = fmaf(zb[4*q+1], e.y, a1);
            a0 = fmaf(za[4*q+2], e.z, a0); a1 = fmaf(zb[4*q+2], e.z, a1);
            a0 = fmaf(za[4*q+3], e.w, a0); a1 = fmaf(zb[4*q+3], e.w, a1);
        }
        const int c = c0 + cc;
        if (a0 > v0) { v0 = a0; i0 = c; }
        if (a1 > v1) { v1 = a1; i1 = c; }
    }
    atomicMax(best + p0, packVK(v0, i0));
    atomicMax(best + p1, packVK(v1, i1));
}

__global__ __launch_bounds__(256) void vq_finish_kernel(
    const u64* __restrict__ best, const float* __restrict__ emb,
    float* __restrict__ zq, float* __restrict__ indOut)
{
    const int p = blockIdx.x * 256 + threadIdx.x;
    const int idx = (int)(~(unsigned)best[p]);

    const float4* e = reinterpret_cast<const float4*>(emb + (size_t)idx * Dc);
    const int b  = p >> 10;
    const int hw = p & (HWc - 1);
    float* o = zq + (size_t)b * Dc * HWc + hw;
#pragma unroll
    for (int q = 0; q < 8; ++q) {
        const float4 v = e[q];
        o[(size_t)(4*q+0) * HWc] = v.x;
        o[(size_t)(4*q+1) * HWc] = v.y;
        o[(size_t)(4*q+2) * HWc] = v.z;
        o[(size_t)(4*q+3) * HWc] = v.w;
    }
    indOut[p] = (float)idx;
}

extern "C" void kernel_launch(void* const* d_in, const int* in_sizes, int n_in,
                              void* d_out, int out_size, void* d_ws, size_t ws_size,
                              hipStream_t stream)
{
    const float* z   = (const float*)d_in[0];
    const float* emb = (const float*)d_in[1];

    float* out    = (float*)d_out;
    float* zq     = out;
    float* indOut = out + (size_t)Bc * Dc * HWc;

    unsigned* pcmax = (unsigned*)d_ws;   // [4096][128] u32 = 2 MB, no init
    const size_t needed = (size_t)POS * NCHUNK * sizeof(unsigned);

    if (ws_size >= needed) {
        hipLaunchKernelGGL(vq_phaseA, dim3(NCHUNK * NPBLK), dim3(512), 0,
                           stream, z, emb, pcmax);
        hipLaunchKernelGGL(vq_phaseB, dim3(POS / 4), dim3(256), 0, stream,
                           z, emb, pcmax, zq, indOut);
    } else {
        u64* best = (u64*)d_ws;
        hipMemsetAsync(best, 0, (size_t)POS * sizeof(u64), stream);
        hipLaunchKernelGGL(vq_scalar, dim3(2048), dim3(256), 0, stream,
                           z, emb, best);
        hipLaunchKernelGGL(vq_finish_kernel, dim3(POS / 256), dim3(256), 0,
                           stream, best, emb, zq, indOut);
    }
}